// Round 4
// baseline (6833.968 us; speedup 1.0000x reference)
//
#include <hip/hip_runtime.h>
#include <float.h>
#include <math.h>

// Problem: z (32,256,32,32) f32, W (8192,256) f32.
// Outputs flat: z_q [0,8388608) | loss [8388608] | index [8388609,8421377) | perp [8421377]
#define OUT_LOSS 8388608
#define OUT_IDX  8388609
#define OUT_PERP 8421377

// Workspace layout (bytes)
#define WS_WBH   0u          // ushort[2097152] bf16 hi of W
#define WS_WBL   4194304u    // ushort[2097152] bf16 lo of W
#define WS_S     8388608u    // float[32768]  ||z||^2 np-pairwise
#define WS_B     8519680u    // float[8192]   ||W||^2 np-pairwise
#define WS_IDX   8552448u    // int[32768]
#define WS_HIST  8683520u    // int[8192]
#define WS_CAND  8716288u    // int[3*32768]
#define WS_FULL  9109504u    // int[32768]
#define WS_CNT   9240576u    // int[2]: 0=cand count, 1=full count
#define WS_LOSS  9240592u    // double

typedef short v8s __attribute__((ext_vector_type(8)));
typedef float v4f __attribute__((ext_vector_type(4)));

__device__ __forceinline__ unsigned short bf16rne(float f) {
  unsigned u = __float_as_uint(f);
  return (unsigned short)((u + 0x7FFFu + ((u >> 16) & 1u)) >> 16);
}
__device__ __forceinline__ float bf16tof(unsigned short h) {
  return __uint_as_float(((unsigned)h) << 16);
}

__global__ void k_zero(int* __restrict__ hist, int* __restrict__ cnt,
                       double* __restrict__ loss) {
  const int i = blockIdx.x * 256 + threadIdx.x;
  if (i < 8192) hist[i] = 0;
  else if (i == 8192) *loss = 0.0;
  else if (i == 8193) cnt[0] = 0;
  else if (i == 8194) cnt[1] = 0;
}

// split W into bf16 hi/lo (row-major, same layout as W)
__global__ __launch_bounds__(256) void k_split(const float* __restrict__ W,
    unsigned short* __restrict__ Wh, unsigned short* __restrict__ Wl) {
  const int o = (blockIdx.x * 256 + threadIdx.x) * 4;   // grid 2048
  const float4 w = *(const float4*)(W + o);
  const float wv[4] = {w.x, w.y, w.z, w.w};
  ushort4 h, l;
  unsigned short* hp = (unsigned short*)&h;
  unsigned short* lp = (unsigned short*)&l;
#pragma unroll
  for (int i = 0; i < 4; ++i) {
    unsigned short hh = bf16rne(wv[i]);
    hp[i] = hh;
    lp[i] = bf16rne(__fsub_rn(wv[i], bf16tof(hh)));
  }
  *(ushort4*)(Wh + o) = h;
  *(ushort4*)(Wl + o) = l;
}

// numpy pairwise sum of squares, n=256 (two 128-blocks, 8 accumulators)
__device__ __forceinline__ float np_sumsq256(const float* __restrict__ base,
                                             const int stride) {
  float h[2];
#pragma unroll
  for (int half = 0; half < 2; ++half) {
    const float* a = base + (size_t)(half * 128) * stride;
    float r[8];
#pragma unroll
    for (int k = 0; k < 8; ++k) { const float v = a[(size_t)k * stride]; r[k] = __fmul_rn(v, v); }
    for (int i = 8; i < 128; i += 8) {
#pragma unroll
      for (int k = 0; k < 8; ++k) {
        const float v = a[(size_t)(i + k) * stride];
        r[k] = __fadd_rn(r[k], __fmul_rn(v, v));
      }
    }
    h[half] = __fadd_rn(
        __fadd_rn(__fadd_rn(r[0], r[1]), __fadd_rn(r[2], r[3])),
        __fadd_rn(__fadd_rn(r[4], r[5]), __fadd_rn(r[6], r[7])));
  }
  return __fadd_rn(h[0], h[1]);
}

__global__ __launch_bounds__(256) void k_sz(const float* __restrict__ z,
                                            float* __restrict__ S) {
  const int n = blockIdx.x * 256 + threadIdx.x;   // grid 128
  S[n] = np_sumsq256(z + (size_t)(n >> 10) * 262144 + (n & 1023), 1024);
}

__global__ __launch_bounds__(256) void k_wsq(const float* __restrict__ W,
                                             float* __restrict__ B) {
  const int j = blockIdx.x * 256 + threadIdx.x;   // grid 32
  B[j] = np_sumsq256(W + (size_t)j * 256, 1);
}

// stable merge of two sorted-3 candidate lists (values + indices for top-2)
__device__ __forceinline__ void merge5(float& a1, int& ai1, float& a2, int& ai2,
                                       float& a3, float b1, int bi1, float b2,
                                       int bi2, float b3) {
  const bool t1 = (b1 < a1) || (b1 == a1 && bi1 < ai1);
  const float w2v = t1 ? b2 : a2; const int w2i = t1 ? bi2 : ai2;
  const float w3v = t1 ? b3 : a3;
  const float l1v = t1 ? a1 : b1; const int l1i = t1 ? ai1 : bi1;
  const float l2v = t1 ? a2 : b2;
  const float n1v = t1 ? b1 : a1; const int n1i = t1 ? bi1 : ai1;
  const bool t2 = (w2v < l1v) || (w2v == l1v && w2i < l1i);
  a1 = n1v; ai1 = n1i;
  a2 = t2 ? w2v : l1v; ai2 = t2 ? w2i : l1i;
  a3 = t2 ? fminf(w3v, l1v) : fminf(w2v, l2v);
}

// Coarse pass: bf16 3-product-split MFMA GEMM + per-pixel stable top-3 of
// d~ = fl(fl(S+B) - 2*C~). Block = 64 px, 4 waves x (64px x 64codes), 32
// code-tiles of 256, K = 8 chunks of 32.
__global__ __launch_bounds__(256) void k_main(const float* __restrict__ z,
    const unsigned short* __restrict__ Wh, const unsigned short* __restrict__ Wl,
    const float* __restrict__ S, const float* __restrict__ B,
    int* __restrict__ idxb, int* __restrict__ cand, int* __restrict__ full,
    int* __restrict__ cnt) {
  __shared__ __align__(16) char smem[40960];
  unsigned short* zsh_h = (unsigned short*)smem;            // [64 px][32 k]
  unsigned short* zsh_l = (unsigned short*)(smem + 4096);
  unsigned short* wsh_h = (unsigned short*)(smem + 8192);   // [256 code][32 k]
  unsigned short* wsh_l = (unsigned short*)(smem + 24576);

  const int t = threadIdx.x;
  const int w = t >> 6;
  const int lane = t & 63;
  const int col = lane & 15;
  const int q = lane >> 4;
  const int n0 = blockIdx.x << 6;            // grid 512
  const float* zb = z + (size_t)(n0 >> 10) * 262144 + (n0 & 1023);

  float m1[16], m2[16], m3[16]; int i1[16], i2[16];
#pragma unroll
  for (int s = 0; s < 16; ++s) {
    m1[s] = FLT_MAX; m2[s] = FLT_MAX; m3[s] = FLT_MAX;
    i1[s] = 0x7fffffff; i2[s] = 0x7fffffff;
  }
  float spx[16];
#pragma unroll
  for (int s = 0; s < 16; ++s)
    spx[s] = S[n0 + (s >> 2) * 16 + q * 4 + (s & 3)];

  const int zpx = t & 63, zkq = t >> 6;      // z staging coords
  float zpre[8]; uint4 wpre[8];

  auto load_chunk = [&](int nct, int kb) {
    const int czo = kb + zkq * 8;
#pragma unroll
    for (int i = 0; i < 8; ++i) zpre[i] = zb[(size_t)(czo + i) * 1024 + zpx];
    const uint4* bh = (const uint4*)(Wh + ((size_t)(nct * 256 + t)) * 256 + kb);
    const uint4* bl = (const uint4*)(Wl + ((size_t)(nct * 256 + t)) * 256 + kb);
#pragma unroll
    for (int i = 0; i < 4; ++i) wpre[i] = bh[i];
#pragma unroll
    for (int i = 0; i < 4; ++i) wpre[4 + i] = bl[i];
  };
  auto store_chunk = [&]() {
    unsigned short hh[8], ll[8];
#pragma unroll
    for (int i = 0; i < 8; ++i) {
      const unsigned short h = bf16rne(zpre[i]);
      hh[i] = h; ll[i] = bf16rne(__fsub_rn(zpre[i], bf16tof(h)));
    }
    *(uint4*)(zsh_h + zpx * 32 + zkq * 8) = *(uint4*)hh;
    *(uint4*)(zsh_l + zpx * 32 + zkq * 8) = *(uint4*)ll;
    uint4* dh = (uint4*)(wsh_h + t * 32);
    uint4* dl = (uint4*)(wsh_l + t * 32);
#pragma unroll
    for (int i = 0; i < 4; ++i) dh[i] = wpre[i];
#pragma unroll
    for (int i = 0; i < 4; ++i) dl[i] = wpre[4 + i];
  };

  load_chunk(0, 0);
  store_chunk();
  __syncthreads();

  for (int ct = 0; ct < 32; ++ct) {
    const int cbase = ct * 256 + w * 64;
    v4f acc[4][4];
#pragma unroll
    for (int pt = 0; pt < 4; ++pt)
#pragma unroll
      for (int nt = 0; nt < 4; ++nt) acc[pt][nt] = (v4f){0.f, 0.f, 0.f, 0.f};

    for (int kc = 0; kc < 8; ++kc) {
      const bool have_next = !(ct == 31 && kc == 7);
      if (have_next) {
        const int nct = (kc < 7) ? ct : ct + 1;
        const int nkb = (kc < 7) ? (kc + 1) * 32 : 0;
        load_chunk(nct, nkb);
      }
      v8s ah[4], al[4];
#pragma unroll
      for (int pt = 0; pt < 4; ++pt) {
        ah[pt] = *(const v8s*)(zsh_h + (pt * 16 + col) * 32 + q * 8);
        al[pt] = *(const v8s*)(zsh_l + (pt * 16 + col) * 32 + q * 8);
      }
#pragma unroll
      for (int nt = 0; nt < 4; ++nt) {
        const int wrow = (w * 64 + nt * 16 + col) * 32 + q * 8;
        const v8s bh = *(const v8s*)(wsh_h + wrow);
        const v8s bl = *(const v8s*)(wsh_l + wrow);
#pragma unroll
        for (int pt = 0; pt < 4; ++pt) {
          acc[pt][nt] = __builtin_amdgcn_mfma_f32_16x16x32_bf16(ah[pt], bh, acc[pt][nt], 0, 0, 0);
          acc[pt][nt] = __builtin_amdgcn_mfma_f32_16x16x32_bf16(ah[pt], bl, acc[pt][nt], 0, 0, 0);
          acc[pt][nt] = __builtin_amdgcn_mfma_f32_16x16x32_bf16(al[pt], bh, acc[pt][nt], 0, 0, 0);
        }
      }
      __syncthreads();
      if (have_next) store_chunk();
      __syncthreads();
    }
    // epilogue: d~ + stable sorted top-3 insert (codes ascend with (ct, nt))
#pragma unroll
    for (int nt = 0; nt < 4; ++nt) {
      const int code = cbase + nt * 16 + col;
      const float bb = B[code];
#pragma unroll
      for (int pt = 0; pt < 4; ++pt) {
        const v4f a = acc[pt][nt];
#pragma unroll
        for (int r = 0; r < 4; ++r) {
          const int s = pt * 4 + r;
          const float d = __fsub_rn(__fadd_rn(spx[s], bb), __fmul_rn(2.f, a[r]));
          const bool c1 = (d < m1[s]);
          const bool c2 = (d < m2[s]);
          const bool c3 = (d < m3[s]);
          m3[s] = c2 ? m2[s] : (c3 ? d : m3[s]);
          m2[s] = c1 ? m1[s] : (c2 ? d : m2[s]);
          i2[s] = c1 ? i1[s] : (c2 ? code : i2[s]);
          m1[s] = c1 ? d : m1[s];
          i1[s] = c1 ? code : i1[s];
        }
      }
    }
  }

  // in-wave merge across the 16 col-lanes of each q-group
#pragma unroll
  for (int s = 0; s < 16; ++s) {
    for (int msk = 1; msk < 16; msk <<= 1) {
      const float b1 = __shfl_xor(m1[s], msk, 16);
      const int  bi1 = __shfl_xor(i1[s], msk, 16);
      const float b2 = __shfl_xor(m2[s], msk, 16);
      const int  bi2 = __shfl_xor(i2[s], msk, 16);
      const float b3 = __shfl_xor(m3[s], msk, 16);
      merge5(m1[s], i1[s], m2[s], i2[s], m3[s], b1, bi1, b2, bi2, b3);
    }
  }
  __syncthreads();           // LDS reuse as merge scratch
  float* sc = (float*)smem;  // [wave][px][5]
  if (col == 0) {
#pragma unroll
    for (int s = 0; s < 16; ++s) {
      const int px = (s >> 2) * 16 + q * 4 + (s & 3);
      const int base = (w * 64 + px) * 5;
      sc[base]     = m1[s];
      sc[base + 1] = __int_as_float(i1[s]);
      sc[base + 2] = m2[s];
      sc[base + 3] = __int_as_float(i2[s]);
      sc[base + 4] = m3[s];
    }
  }
  __syncthreads();
  if (t < 64) {
    float A1 = sc[t * 5], A2 = sc[t * 5 + 2], A3 = sc[t * 5 + 4];
    int AI1 = __float_as_int(sc[t * 5 + 1]), AI2 = __float_as_int(sc[t * 5 + 3]);
    for (int wv = 1; wv < 4; ++wv) {
      const int base = (wv * 64 + t) * 5;
      merge5(A1, AI1, A2, AI2, A3, sc[base], __float_as_int(sc[base + 1]),
             sc[base + 2], __float_as_int(sc[base + 3]), sc[base + 4]);
    }
    const int n = n0 + t;
    idxb[n] = AI1;
    const float window = 5.0f * ldexpf(1.0f, ilogbf(A1) - 23);
    if (A2 <= A1 + window) {
      if (A3 <= A1 + window) {
        const int p = atomicAdd(&cnt[1], 1);
        full[p & 32767] = n;
      } else {
        const int p = atomicAdd(&cnt[0], 1);
        cand[3 * (p & 32767)] = n;
        cand[3 * (p & 32767) + 1] = AI1;
        cand[3 * (p & 32767) + 2] = AI2;
      }
    }
  }
}

// exact np-chain re-eval of the two candidates
__global__ __launch_bounds__(256) void k_cand(const float* __restrict__ z,
    const float* __restrict__ W, const float* __restrict__ S,
    const float* __restrict__ B, const int* __restrict__ cand,
    const int* __restrict__ cnt, int* __restrict__ idxb) {
  const int cN = min(cnt[0], 32768);
  for (int e = blockIdx.x * 256 + threadIdx.x; e < cN; e += 64 * 256) {
    const int n = cand[3 * e], ca = cand[3 * e + 1], cb = cand[3 * e + 2];
    const float* zp = z + (size_t)(n >> 10) * 262144 + (n & 1023);
    const float* wa = W + (size_t)ca * 256;
    const float* wb = W + (size_t)cb * 256;
    float a1 = 0.f, a2 = 0.f;
    for (int c = 0; c < 256; ++c) {
      const float zv = zp[(size_t)c * 1024];
      a1 = __builtin_fmaf(zv, wa[c], a1);
      a2 = __builtin_fmaf(zv, wb[c], a2);
    }
    const float d1 = __fsub_rn(__fadd_rn(S[n], B[ca]), __fmul_rn(2.f, a1));
    const float d2 = __fsub_rn(__fadd_rn(S[n], B[cb]), __fmul_rn(2.f, a2));
    idxb[n] = (d1 < d2) ? ca : ((d2 < d1) ? cb : min(ca, cb));
  }
}

// exact np-chain full argmin for overflow pixels
__global__ __launch_bounds__(256) void k_full(const float* __restrict__ z,
    const float* __restrict__ W, const float* __restrict__ S,
    const float* __restrict__ B, const int* __restrict__ full,
    const int* __restrict__ cnt, int* __restrict__ idxb) {
  __shared__ float zr[256];
  __shared__ float bv[256];
  __shared__ int bi[256];
  const int t = threadIdx.x;
  const int fN = min(cnt[1], 32768);
  for (int f = blockIdx.x; f < fN; f += 64) {
    __syncthreads();
    const int n = full[f];
    zr[t] = z[(size_t)(n >> 10) * 262144 + (size_t)t * 1024 + (n & 1023)];
    __syncthreads();
    const float sn = S[n];
    float bm = FLT_MAX; int bj = 0x7fffffff;
    for (int rep = 0; rep < 32; ++rep) {
      const int j = rep * 256 + t;
      const float* wr = W + (size_t)j * 256;
      float a = 0.f;
      for (int c = 0; c < 256; ++c) a = __builtin_fmaf(zr[c], wr[c], a);
      const float d = __fsub_rn(__fadd_rn(sn, B[j]), __fmul_rn(2.f, a));
      if (d < bm) { bm = d; bj = j; }
    }
    bv[t] = bm; bi[t] = bj;
    __syncthreads();
    if (t == 0) {
      float m = bv[0]; int mi = bi[0];
      for (int s2 = 1; s2 < 256; ++s2)
        if (bv[s2] < m || (bv[s2] == m && bi[s2] < mi)) { m = bv[s2]; mi = bi[s2]; }
      idxb[n] = mi;
    }
  }
}

// z_q gather (STE rounding) + loss + histogram + index output
__global__ __launch_bounds__(256) void k_zq(const float* __restrict__ z,
    const float* __restrict__ W, const int* __restrict__ idxb,
    float* __restrict__ out, double* __restrict__ loss, int* __restrict__ hist) {
  __shared__ float red[256];
  const int t = threadIdx.x;
  const int tx = t & 63, ty = t >> 6;
  const int n0 = blockIdx.x << 6;            // grid 512
  const int n = n0 + tx;
  const int b = n >> 10;
  const int p = n & 1023;
  const int myidx = idxb[n];
  const float* wrow = W + (size_t)myidx * 256;
  float lsum = 0.f;
#pragma unroll 4
  for (int cc = 0; cc < 64; ++cc) {
    const int c = ty * 64 + cc;
    const float qv = wrow[c];
    const size_t off = (size_t)b * 262144 + (size_t)c * 1024 + p;
    const float zv = z[off];
    const float d = __fsub_rn(qv, zv);
    lsum = __builtin_fmaf(d, d, lsum);
    out[off] = __fadd_rn(zv, d);
  }
  red[t] = lsum;
  __syncthreads();
  for (int o = 128; o > 0; o >>= 1) {
    if (t < o) red[t] += red[t + o];
    __syncthreads();
  }
  if (t == 0) atomicAdd(loss, (double)red[0]);
  if (ty == 0) atomicAdd(&hist[myidx], 1);
  if (ty == 1) out[OUT_IDX + n] = (float)myidx;
}

__global__ void k_final(const int* __restrict__ hist,
                        const double* __restrict__ loss,
                        float* __restrict__ out) {
  __shared__ double sh[256];
  const int t = threadIdx.x;
  double s = 0.0;
  for (int j = t; j < 8192; j += 256) {
    const double e = (double)hist[j] / 32768.0;
    s += e * log(e + 1e-10);
  }
  sh[t] = s;
  __syncthreads();
  for (int off = 128; off > 0; off >>= 1) {
    if (t < off) sh[t] += sh[t + off];
    __syncthreads();
  }
  if (t == 0) {
    out[OUT_PERP] = (float)exp(-sh[0]);
    out[OUT_LOSS] = (float)(1.25 * (*loss) / 8388608.0);
  }
}

extern "C" void kernel_launch(void* const* d_in, const int* in_sizes, int n_in,
                              void* d_out, int out_size, void* d_ws, size_t ws_size,
                              hipStream_t stream) {
  const float* z = (const float*)d_in[0];
  const float* W = (const float*)d_in[1];
  float* out = (float*)d_out;
  char* ws = (char*)d_ws;
  unsigned short* Wbh = (unsigned short*)(ws + WS_WBH);
  unsigned short* Wbl = (unsigned short*)(ws + WS_WBL);
  float*  S    = (float*)(ws + WS_S);
  float*  B    = (float*)(ws + WS_B);
  int*    idxb = (int*)(ws + WS_IDX);
  int*    hist = (int*)(ws + WS_HIST);
  int*    cand = (int*)(ws + WS_CAND);
  int*    full = (int*)(ws + WS_FULL);
  int*    cnt  = (int*)(ws + WS_CNT);
  double* loss = (double*)(ws + WS_LOSS);

  hipLaunchKernelGGL(k_zero,  dim3(33),   dim3(256), 0, stream, hist, cnt, loss);
  hipLaunchKernelGGL(k_split, dim3(2048), dim3(256), 0, stream, W, Wbh, Wbl);
  hipLaunchKernelGGL(k_sz,    dim3(128),  dim3(256), 0, stream, z, S);
  hipLaunchKernelGGL(k_wsq,   dim3(32),   dim3(256), 0, stream, W, B);
  hipLaunchKernelGGL(k_main,  dim3(512),  dim3(256), 0, stream, z, Wbh, Wbl, S, B,
                     idxb, cand, full, cnt);
  hipLaunchKernelGGL(k_cand,  dim3(64),   dim3(256), 0, stream, z, W, S, B, cand, cnt, idxb);
  hipLaunchKernelGGL(k_full,  dim3(64),   dim3(256), 0, stream, z, W, S, B, full, cnt, idxb);
  hipLaunchKernelGGL(k_zq,    dim3(512),  dim3(256), 0, stream, z, W, idxb, out, loss, hist);
  hipLaunchKernelGGL(k_final, dim3(1),    dim3(256), 0, stream, hist, loss, out);
}

// Round 5
// 2357.320 us; speedup vs baseline: 2.8990x; 2.8990x over previous
//
#include <hip/hip_runtime.h>
#include <float.h>
#include <math.h>

// Problem: z (32,256,32,32) f32, W (8192,256) f32.
// Outputs flat: z_q [0,8388608) | loss [8388608] | index [8388609,8421377) | perp [8421377]
#define OUT_LOSS 8388608
#define OUT_IDX  8388609
#define OUT_PERP 8421377

// Workspace layout (bytes)  (~38.9 MB total)
#define WS_ZH    0ull          // ushort[32768*256]  bf16 hi of z, [n][k]
#define WS_ZL    16777216ull   // ushort[32768*256]  bf16 lo of z
#define WS_WH    33554432ull   // ushort[8192*256]   bf16 hi of W, [j][k]
#define WS_S     37748736ull   // float[32768]  ||z||^2 np-pairwise
#define WS_B     37879808ull   // float[8192]   ||W||^2 np-pairwise
#define WS_MAXW  37912576ull   // uint           max_j B_j (bits)
#define WS_IDX   37912640ull   // int[32768]
#define WS_HIST  38043712ull   // int[8192]
#define WS_CAND  38076480ull   // int[3*32768]
#define WS_FULL  38469696ull   // int[32768]
#define WS_FKEY  38600768ull   // u64[32768]
#define WS_CNT   38862912ull   // int[2]
#define WS_LOSS  38862920ull   // double

typedef short v8s __attribute__((ext_vector_type(8)));
typedef float v4f __attribute__((ext_vector_type(4)));

__device__ __forceinline__ unsigned short bf16rne(float f) {
  unsigned u = __float_as_uint(f);
  return (unsigned short)((u + 0x7FFFu + ((u >> 16) & 1u)) >> 16);
}
__device__ __forceinline__ float bf16tof(unsigned short h) {
  return __uint_as_float(((unsigned)h) << 16);
}

__global__ void k_zero(int* __restrict__ hist, unsigned long long* __restrict__ fkey,
                       int* __restrict__ cnt, double* __restrict__ loss,
                       unsigned* __restrict__ maxw) {
  const int i = blockIdx.x * 256 + threadIdx.x;   // grid 161
  if (i < 8192) hist[i] = 0;
  else if (i < 40960) fkey[i - 8192] = ~0ull;
  else if (i == 40960) cnt[0] = 0;
  else if (i == 40961) cnt[1] = 0;
  else if (i == 40962) *loss = 0.0;
  else if (i == 40963) *maxw = 0u;
}

// W -> bf16 hi (row-major [j][k])
__global__ __launch_bounds__(256) void k_split(const float* __restrict__ W,
                                               unsigned short* __restrict__ Wh) {
  const int o = (blockIdx.x * 256 + threadIdx.x) * 4;   // grid 2048
  const float4 w = *(const float4*)(W + o);
  const float wv[4] = {w.x, w.y, w.z, w.w};
  ushort4 h;
  unsigned short* hp = (unsigned short*)&h;
#pragma unroll
  for (int i = 0; i < 4; ++i) hp[i] = bf16rne(wv[i]);
  *(ushort4*)(Wh + o) = h;
}

// z (32,256,32,32) -> Zh/Zl [n][k] bf16 (n = b*1024 + p), LDS transpose.
__global__ __launch_bounds__(256) void k_splitz(const float* __restrict__ z,
    unsigned short* __restrict__ Zh, unsigned short* __restrict__ Zl) {
  __shared__ __align__(16) unsigned short zt[64][264];
  const int t = threadIdx.x;
  const int n0 = blockIdx.x << 6;              // grid 512
  const int b = n0 >> 10, p0 = n0 & 1023;
  const int cpart = t >> 6, px = t & 63;
  const int orow = t >> 2, opart = t & 3;      // out: 64 rows x 4x128B parts
  for (int pass = 0; pass < 2; ++pass) {
    __syncthreads();
    for (int cc = 0; cc < 64; ++cc) {
      const int c = cc * 4 + cpart;
      const float v = z[(size_t)b * 262144 + (size_t)c * 1024 + p0 + px];
      const unsigned short h = bf16rne(v);
      zt[px][c] = pass ? bf16rne(__fsub_rn(v, bf16tof(h))) : h;
    }
    __syncthreads();
    unsigned short* dst = (pass ? Zl : Zh) + ((size_t)(n0 + orow) * 256 + opart * 64);
#pragma unroll
    for (int i = 0; i < 8; ++i)
      *(uint4*)(dst + i * 8) = *(const uint4*)&zt[orow][opart * 64 + i * 8];
  }
}

// numpy pairwise sum of squares, n=256 (two 128-blocks, 8 accumulators)
__device__ __forceinline__ float np_sumsq256(const float* __restrict__ base,
                                             const int stride) {
  float h[2];
#pragma unroll
  for (int half = 0; half < 2; ++half) {
    const float* a = base + (size_t)(half * 128) * stride;
    float r[8];
#pragma unroll
    for (int k = 0; k < 8; ++k) { const float v = a[(size_t)k * stride]; r[k] = __fmul_rn(v, v); }
    for (int i = 8; i < 128; i += 8) {
#pragma unroll
      for (int k = 0; k < 8; ++k) {
        const float v = a[(size_t)(i + k) * stride];
        r[k] = __fadd_rn(r[k], __fmul_rn(v, v));
      }
    }
    h[half] = __fadd_rn(
        __fadd_rn(__fadd_rn(r[0], r[1]), __fadd_rn(r[2], r[3])),
        __fadd_rn(__fadd_rn(r[4], r[5]), __fadd_rn(r[6], r[7])));
  }
  return __fadd_rn(h[0], h[1]);
}

__global__ __launch_bounds__(256) void k_sz(const float* __restrict__ z,
                                            float* __restrict__ S) {
  const int n = blockIdx.x * 256 + threadIdx.x;   // grid 128
  S[n] = np_sumsq256(z + (size_t)(n >> 10) * 262144 + (n & 1023), 1024);
}

__global__ __launch_bounds__(256) void k_wsq(const float* __restrict__ W,
                                             float* __restrict__ B,
                                             unsigned* __restrict__ maxw) {
  const int j = blockIdx.x * 256 + threadIdx.x;   // grid 32
  const float b = np_sumsq256(W + (size_t)j * 256, 1);
  B[j] = b;
  atomicMax(maxw, __float_as_uint(b));
}

// stable merge of two sorted-3 lists (values + indices for top-2)
__device__ __forceinline__ void merge5(float& a1, int& ai1, float& a2, int& ai2,
                                       float& a3, float b1, int bi1, float b2,
                                       int bi2, float b3) {
  const bool t1 = (b1 < a1) || (b1 == a1 && bi1 < ai1);
  const float w2v = t1 ? b2 : a2; const int w2i = t1 ? bi2 : ai2;
  const float w3v = t1 ? b3 : a3;
  const float l1v = t1 ? a1 : b1; const int l1i = t1 ? ai1 : bi1;
  const float l2v = t1 ? a2 : b2;
  const float n1v = t1 ? b1 : a1; const int n1i = t1 ? bi1 : ai1;
  const bool t2 = (w2v < l1v) || (w2v == l1v && w2i < l1i);
  a1 = n1v; ai1 = n1i;
  a2 = t2 ? w2v : l1v; ai2 = t2 ? w2i : l1i;
  a3 = t2 ? fminf(w3v, l1v) : fminf(w2v, l2v);
}

// Coarse pass: C~ = (zh+zl)*wh via 2 MFMAs, d~ = fl(fl(S+B)-2C~), top-3/pixel.
// Block: 512 thr (8 waves), 64 px, A(z) LDS-resident full-K, B dbuf per 32-k chunk.
// Waves: phalf=w>>2 (32 px), strip=w&3 (128 codes of each 512-code tile).
#define A_STRIDE 272
#define AH_OFF 0
#define AL_OFF 34816
#define B0_OFF 69632
#define B1_OFF 110592
#define SC_OFF 69632
__global__ __launch_bounds__(512, 2) void k_main(
    const unsigned short* __restrict__ Zh, const unsigned short* __restrict__ Zl,
    const unsigned short* __restrict__ Wh, const float* __restrict__ S,
    const float* __restrict__ B, const unsigned* __restrict__ maxw,
    int* __restrict__ idxb, int* __restrict__ cand, int* __restrict__ full,
    int* __restrict__ cnt) {
  extern __shared__ __align__(16) char smem[];
  unsigned short* Ah = (unsigned short*)(smem + AH_OFF);
  unsigned short* Al = (unsigned short*)(smem + AL_OFF);
  const int t = threadIdx.x;
  const int w = t >> 6, lane = t & 63, col = lane & 15, q = lane >> 4;
  const int phalf = w >> 2, strip = w & 3;
  const int n0 = blockIdx.x << 6;             // grid 512

  // ---- stage A (once): 64 rows x 256 k, hi+lo ----
  {
    const int row = t >> 3, seg = t & 7;
    const uint4* sh = (const uint4*)(Zh + (size_t)(n0 + row) * 256 + seg * 32);
    const uint4* sl = (const uint4*)(Zl + (size_t)(n0 + row) * 256 + seg * 32);
    uint4* dh = (uint4*)((char*)Ah + row * (A_STRIDE * 2) + seg * 64);
    uint4* dl = (uint4*)((char*)Al + row * (A_STRIDE * 2) + seg * 64);
#pragma unroll
    for (int i = 0; i < 4; ++i) dh[i] = sh[i];
#pragma unroll
    for (int i = 0; i < 4; ++i) dl[i] = sl[i];
  }
  // ---- B prologue: load (ct=0,kc=0) chunk ----
  uint4 bpre[4];
  {
    const uint4* src = (const uint4*)(Wh + (size_t)t * 256);
#pragma unroll
    for (int i = 0; i < 4; ++i) bpre[i] = src[i];
  }
  __syncthreads();   // A visible
  {
    uint4* dst = (uint4*)(smem + B0_OFF + t * 80);
#pragma unroll
    for (int i = 0; i < 4; ++i) dst[i] = bpre[i];
  }
  __syncthreads();

  float spx[8];
#pragma unroll
  for (int s = 0; s < 8; ++s)
    spx[s] = S[n0 + phalf * 32 + (s >> 2) * 16 + q * 4 + (s & 3)];

  float m1[8], m2[8], m3[8]; int i1[8], i2[8];
#pragma unroll
  for (int s = 0; s < 8; ++s) {
    m1[s] = FLT_MAX; m2[s] = FLT_MAX; m3[s] = FLT_MAX;
    i1[s] = 0x7fffffff; i2[s] = 0x7fffffff;
  }

  v4f acc[2][8];
#pragma unroll
  for (int pt = 0; pt < 2; ++pt)
#pragma unroll
    for (int nt = 0; nt < 8; ++nt) acc[pt][nt] = (v4f){0.f, 0.f, 0.f, 0.f};

  for (int it = 0; it < 128; ++it) {          // 16 ct x 8 kc
    const int ct = it >> 3, kc = it & 7;
    if (it < 127) {                            // prefetch next chunk
      const int nct = (it + 1) >> 3, nkc = (it + 1) & 7;
      const uint4* src = (const uint4*)(Wh + (size_t)(nct * 512 + t) * 256 + nkc * 32);
#pragma unroll
      for (int i = 0; i < 4; ++i) bpre[i] = src[i];
    }
    const char* bbuf = smem + ((it & 1) ? B1_OFF : B0_OFF);
    v8s ah[2], al[2];
#pragma unroll
    for (int pt = 0; pt < 2; ++pt) {
      const int arow = phalf * 32 + pt * 16 + col;
      ah[pt] = *(const v8s*)((const char*)Ah + arow * (A_STRIDE * 2) + kc * 64 + q * 16);
      al[pt] = *(const v8s*)((const char*)Al + arow * (A_STRIDE * 2) + kc * 64 + q * 16);
    }
#pragma unroll
    for (int nt = 0; nt < 8; ++nt) {
      const v8s bh = *(const v8s*)(bbuf + (strip * 128 + nt * 16 + col) * 80 + q * 16);
#pragma unroll
      for (int pt = 0; pt < 2; ++pt) {
        acc[pt][nt] = __builtin_amdgcn_mfma_f32_16x16x32_bf16(ah[pt], bh, acc[pt][nt], 0, 0, 0);
        acc[pt][nt] = __builtin_amdgcn_mfma_f32_16x16x32_bf16(al[pt], bh, acc[pt][nt], 0, 0, 0);
      }
    }
    if (it < 127) {                            // store prefetched into other buf
      uint4* dst = (uint4*)(smem + (((it + 1) & 1) ? B1_OFF : B0_OFF) + t * 80);
#pragma unroll
      for (int i = 0; i < 4; ++i) dst[i] = bpre[i];
    }
    __syncthreads();
    if (kc == 7) {                             // epilogue for this 512-code tile
#pragma unroll
      for (int nt = 0; nt < 8; ++nt) {
        const int code = ct * 512 + strip * 128 + nt * 16 + col;
        const float bb = B[code];
#pragma unroll
        for (int pt = 0; pt < 2; ++pt) {
          const v4f a = acc[pt][nt];
#pragma unroll
          for (int r = 0; r < 4; ++r) {
            const int s = pt * 4 + r;
            const float d = __fsub_rn(__fadd_rn(spx[s], bb), __fmul_rn(2.f, a[r]));
            const bool c1 = (d < m1[s]);
            const bool c2 = (d < m2[s]);
            const bool c3 = (d < m3[s]);
            m3[s] = c2 ? m2[s] : (c3 ? d : m3[s]);
            m2[s] = c1 ? m1[s] : (c2 ? d : m2[s]);
            i2[s] = c1 ? i1[s] : (c2 ? code : i2[s]);
            m1[s] = c1 ? d : m1[s];
            i1[s] = c1 ? code : i1[s];
          }
        }
#pragma unroll
        for (int pt = 0; pt < 2; ++pt) acc[pt][nt] = (v4f){0.f, 0.f, 0.f, 0.f};
      }
    }
  }

  // in-wave merge across the 16 col-lanes
#pragma unroll
  for (int s = 0; s < 8; ++s) {
    for (int msk = 1; msk < 16; msk <<= 1) {
      const float b1 = __shfl_xor(m1[s], msk, 16);
      const int  bi1 = __shfl_xor(i1[s], msk, 16);
      const float b2 = __shfl_xor(m2[s], msk, 16);
      const int  bi2 = __shfl_xor(i2[s], msk, 16);
      const float b3 = __shfl_xor(m3[s], msk, 16);
      merge5(m1[s], i1[s], m2[s], i2[s], m3[s], b1, bi1, b2, bi2, b3);
    }
  }
  __syncthreads();
  float* sc = (float*)(smem + SC_OFF);        // [px][strip][5]
  if (col == 0) {
#pragma unroll
    for (int s = 0; s < 8; ++s) {
      const int px = phalf * 32 + (s >> 2) * 16 + q * 4 + (s & 3);
      const int base = (px * 4 + strip) * 5;
      sc[base]     = m1[s];
      sc[base + 1] = __int_as_float(i1[s]);
      sc[base + 2] = m2[s];
      sc[base + 3] = __int_as_float(i2[s]);
      sc[base + 4] = m3[s];
    }
  }
  __syncthreads();
  if (t < 64) {
    const int base0 = t * 20;
    float A1 = sc[base0], A2 = sc[base0 + 2], A3 = sc[base0 + 4];
    int AI1 = __float_as_int(sc[base0 + 1]), AI2 = __float_as_int(sc[base0 + 3]);
    for (int st = 1; st < 4; ++st) {
      const int base = base0 + st * 5;
      merge5(A1, AI1, A2, AI2, A3, sc[base], __float_as_int(sc[base + 1]),
             sc[base + 2], __float_as_int(sc[base + 3]), sc[base + 4]);
    }
    const int n = n0 + t;
    idxb[n] = AI1;
    // window: 2*(2^-9*||z||*max||w|| + slack) + 2 ulp(m1)
    const float nw = sqrtf(S[n]) * sqrtf(__uint_as_float(*maxw));
    const float win = 2.0f * (0.001953125f * nw + 1e-6f)
                    + 2.0f * ldexpf(1.0f, ilogbf(fmaxf(A1, 1e-30f)) - 23);
    if (A2 <= A1 + win) {
      if (A3 <= A1 + win) {
        const int p = atomicAdd(&cnt[1], 1);
        full[p] = n;
      } else {
        const int p = atomicAdd(&cnt[0], 1);
        cand[3 * p] = n; cand[3 * p + 1] = AI1; cand[3 * p + 2] = AI2;
      }
    }
  }
}

// exact np-chain re-eval of the two candidates
__global__ __launch_bounds__(256) void k_cand(const float* __restrict__ z,
    const float* __restrict__ W, const float* __restrict__ S,
    const float* __restrict__ B, const int* __restrict__ cand,
    const int* __restrict__ cnt, int* __restrict__ idxb) {
  const int e = blockIdx.x * 256 + threadIdx.x;   // grid 128
  if (e >= cnt[0]) return;
  const int n = cand[3 * e], ca = cand[3 * e + 1], cb = cand[3 * e + 2];
  const float* zp = z + (size_t)(n >> 10) * 262144 + (n & 1023);
  const float* wa = W + (size_t)ca * 256;
  const float* wb = W + (size_t)cb * 256;
  float a1 = 0.f, a2 = 0.f;
  for (int c = 0; c < 256; ++c) {
    const float zv = zp[(size_t)c * 1024];
    a1 = __builtin_fmaf(zv, wa[c], a1);
    a2 = __builtin_fmaf(zv, wb[c], a2);
  }
  const float d1 = __fsub_rn(__fadd_rn(S[n], B[ca]), __fmul_rn(2.f, a1));
  const float d2 = __fsub_rn(__fadd_rn(S[n], B[cb]), __fmul_rn(2.f, a2));
  idxb[n] = (d1 < d2) ? ca : ((d2 < d1) ? cb : min(ca, cb));
}

// exact full argmin: block per (flagged pixel x 256-code slice), atomicMin on
// packed (d_bits<<13 | j) -> min d, then min j (np first-occurrence).
__global__ __launch_bounds__(256) void k_full(const float* __restrict__ z,
    const float* __restrict__ W, const float* __restrict__ S,
    const float* __restrict__ B, const int* __restrict__ full,
    const int* __restrict__ cnt, unsigned long long* __restrict__ fkey) {
  __shared__ float zsh[256];
  const int t = threadIdx.x;
  const int total = cnt[1] * 32;
  for (int e = blockIdx.x; e < total; e += 2048) {
    const int f = e >> 5, sl = e & 31;
    const int n = full[f];
    __syncthreads();
    zsh[t] = z[(size_t)(n >> 10) * 262144 + (size_t)t * 1024 + (n & 1023)];
    __syncthreads();
    const int j = sl * 256 + t;
    const float* wr = W + (size_t)j * 256;
    float a = 0.f;
    for (int c = 0; c < 256; ++c) a = __builtin_fmaf(zsh[c], wr[c], a);
    const float d = __fsub_rn(__fadd_rn(S[n], B[j]), __fmul_rn(2.f, a));
    const unsigned long long key =
        (((unsigned long long)__float_as_uint(d)) << 13) | (unsigned)j;
    atomicMin(&fkey[f], key);
  }
}

__global__ __launch_bounds__(256) void k_fullfin(const int* __restrict__ full,
    const int* __restrict__ cnt, const unsigned long long* __restrict__ fkey,
    int* __restrict__ idxb) {
  const int f = blockIdx.x * 256 + threadIdx.x;   // grid 128
  if (f < cnt[1]) idxb[full[f]] = (int)(fkey[f] & 8191ull);
}

// z_q gather (STE rounding) + loss + histogram + index output
__global__ __launch_bounds__(256) void k_zq(const float* __restrict__ z,
    const float* __restrict__ W, const int* __restrict__ idxb,
    float* __restrict__ out, double* __restrict__ loss, int* __restrict__ hist) {
  __shared__ float red[256];
  const int t = threadIdx.x;
  const int tx = t & 63, ty = t >> 6;
  const int n0 = blockIdx.x << 6;            // grid 512
  const int n = n0 + tx;
  const int b = n >> 10;
  const int p = n & 1023;
  const int myidx = idxb[n];
  const float* wrow = W + (size_t)myidx * 256;
  float lsum = 0.f;
#pragma unroll 4
  for (int cc = 0; cc < 64; ++cc) {
    const int c = ty * 64 + cc;
    const float qv = wrow[c];
    const size_t off = (size_t)b * 262144 + (size_t)c * 1024 + p;
    const float zv = z[off];
    const float d = __fsub_rn(qv, zv);
    lsum = __builtin_fmaf(d, d, lsum);
    out[off] = __fadd_rn(zv, d);
  }
  red[t] = lsum;
  __syncthreads();
  for (int o = 128; o > 0; o >>= 1) {
    if (t < o) red[t] += red[t + o];
    __syncthreads();
  }
  if (t == 0) atomicAdd(loss, (double)red[0]);
  if (ty == 0) atomicAdd(&hist[myidx], 1);
  if (ty == 1) out[OUT_IDX + n] = (float)myidx;
}

__global__ void k_final(const int* __restrict__ hist,
                        const double* __restrict__ loss,
                        float* __restrict__ out) {
  __shared__ double sh[256];
  const int t = threadIdx.x;
  double s = 0.0;
  for (int j = t; j < 8192; j += 256) {
    const double e = (double)hist[j] / 32768.0;
    s += e * log(e + 1e-10);
  }
  sh[t] = s;
  __syncthreads();
  for (int off = 128; off > 0; off >>= 1) {
    if (t < off) sh[t] += sh[t + off];
    __syncthreads();
  }
  if (t == 0) {
    out[OUT_PERP] = (float)exp(-sh[0]);
    out[OUT_LOSS] = (float)(1.25 * (*loss) / 8388608.0);
  }
}

extern "C" void kernel_launch(void* const* d_in, const int* in_sizes, int n_in,
                              void* d_out, int out_size, void* d_ws, size_t ws_size,
                              hipStream_t stream) {
  const float* z = (const float*)d_in[0];
  const float* W = (const float*)d_in[1];
  float* out = (float*)d_out;
  char* ws = (char*)d_ws;
  unsigned short* Zh = (unsigned short*)(ws + WS_ZH);
  unsigned short* Zl = (unsigned short*)(ws + WS_ZL);
  unsigned short* Wh = (unsigned short*)(ws + WS_WH);
  float*  S    = (float*)(ws + WS_S);
  float*  B    = (float*)(ws + WS_B);
  unsigned* maxw = (unsigned*)(ws + WS_MAXW);
  int*    idxb = (int*)(ws + WS_IDX);
  int*    hist = (int*)(ws + WS_HIST);
  int*    cand = (int*)(ws + WS_CAND);
  int*    full = (int*)(ws + WS_FULL);
  unsigned long long* fkey = (unsigned long long*)(ws + WS_FKEY);
  int*    cnt  = (int*)(ws + WS_CNT);
  double* loss = (double*)(ws + WS_LOSS);

  hipLaunchKernelGGL(k_zero,    dim3(161),  dim3(256), 0, stream, hist, fkey, cnt, loss, maxw);
  hipLaunchKernelGGL(k_split,   dim3(2048), dim3(256), 0, stream, W, Wh);
  hipLaunchKernelGGL(k_splitz,  dim3(512),  dim3(256), 0, stream, z, Zh, Zl);
  hipLaunchKernelGGL(k_sz,      dim3(128),  dim3(256), 0, stream, z, S);
  hipLaunchKernelGGL(k_wsq,     dim3(32),   dim3(256), 0, stream, W, B, maxw);
  hipLaunchKernelGGL(k_main,    dim3(512),  dim3(512), 151552, stream,
                     Zh, Zl, Wh, S, B, maxw, idxb, cand, full, cnt);
  hipLaunchKernelGGL(k_cand,    dim3(128),  dim3(256), 0, stream, z, W, S, B, cand, cnt, idxb);
  hipLaunchKernelGGL(k_full,    dim3(2048), dim3(256), 0, stream, z, W, S, B, full, cnt, fkey);
  hipLaunchKernelGGL(k_fullfin, dim3(128),  dim3(256), 0, stream, full, cnt, fkey, idxb);
  hipLaunchKernelGGL(k_zq,      dim3(512),  dim3(256), 0, stream, z, W, idxb, out, loss, hist);
  hipLaunchKernelGGL(k_final,   dim3(1),    dim3(256), 0, stream, hist, loss, out);
}

// Round 6
// 1495.932 us; speedup vs baseline: 4.5684x; 1.5758x over previous
//
#include <hip/hip_runtime.h>
#include <float.h>
#include <math.h>

// Problem: z (32,256,32,32) f32, W (8192,256) f32.
// Outputs flat: z_q [0,8388608) | loss [8388608] | index [8388609,8421377) | perp [8421377]
#define OUT_LOSS 8388608
#define OUT_IDX  8388609
#define OUT_PERP 8421377

// Workspace layout (bytes)  (~38.9 MB total)
#define WS_ZH    0ull          // ushort[32768*256]  bf16 hi of z, [n][k]
#define WS_ZL    16777216ull   // ushort[32768*256]  bf16 lo of z
#define WS_WH    33554432ull   // ushort[8192*256]   bf16 hi of W, [j][k]
#define WS_S     37748736ull   // float[32768]  ||z||^2 np-pairwise
#define WS_B     37879808ull   // float[8192]   ||W||^2 np-pairwise
#define WS_MAXW  37912576ull   // uint           max_j B_j (bits)
#define WS_IDX   37912640ull   // int[32768]
#define WS_HIST  38043712ull   // int[8192]
#define WS_CAND  38076480ull   // int[3*32768]
#define WS_FULL  38469696ull   // int[32768]
#define WS_FKEY  38600768ull   // u64[32768]
#define WS_CNT   38862912ull   // int[2]
#define WS_LOSS  38862920ull   // double

typedef short v8s __attribute__((ext_vector_type(8)));
typedef float v4f __attribute__((ext_vector_type(4)));

__device__ __forceinline__ unsigned short bf16rne(float f) {
  unsigned u = __float_as_uint(f);
  return (unsigned short)((u + 0x7FFFu + ((u >> 16) & 1u)) >> 16);
}
__device__ __forceinline__ float bf16tof(unsigned short h) {
  return __uint_as_float(((unsigned)h) << 16);
}

__global__ void k_zero(int* __restrict__ hist, unsigned long long* __restrict__ fkey,
                       int* __restrict__ cnt, double* __restrict__ loss,
                       unsigned* __restrict__ maxw) {
  const int i = blockIdx.x * 256 + threadIdx.x;   // grid 161
  if (i < 8192) hist[i] = 0;
  else if (i < 40960) fkey[i - 8192] = ~0ull;
  else if (i == 40960) cnt[0] = 0;
  else if (i == 40961) cnt[1] = 0;
  else if (i == 40962) *loss = 0.0;
  else if (i == 40963) *maxw = 0u;
}

// W -> bf16 hi (row-major [j][k])
__global__ __launch_bounds__(256) void k_split(const float* __restrict__ W,
                                               unsigned short* __restrict__ Wh) {
  const int o = (blockIdx.x * 256 + threadIdx.x) * 4;   // grid 2048
  const float4 w = *(const float4*)(W + o);
  const float wv[4] = {w.x, w.y, w.z, w.w};
  ushort4 h;
  unsigned short* hp = (unsigned short*)&h;
#pragma unroll
  for (int i = 0; i < 4; ++i) hp[i] = bf16rne(wv[i]);
  *(ushort4*)(Wh + o) = h;
}

// z (32,256,32,32) -> Zh/Zl [n][k] bf16 (n = b*1024 + p), LDS transpose.
__global__ __launch_bounds__(256) void k_splitz(const float* __restrict__ z,
    unsigned short* __restrict__ Zh, unsigned short* __restrict__ Zl) {
  __shared__ __align__(16) unsigned short zt[64][264];
  const int t = threadIdx.x;
  const int n0 = blockIdx.x << 6;              // grid 512
  const int b = n0 >> 10, p0 = n0 & 1023;
  const int cpart = t >> 6, px = t & 63;
  const int orow = t >> 2, opart = t & 3;      // out: 64 rows x 4x128B parts
  for (int pass = 0; pass < 2; ++pass) {
    __syncthreads();
    for (int cc = 0; cc < 64; ++cc) {
      const int c = cc * 4 + cpart;
      const float v = z[(size_t)b * 262144 + (size_t)c * 1024 + p0 + px];
      const unsigned short h = bf16rne(v);
      zt[px][c] = pass ? bf16rne(__fsub_rn(v, bf16tof(h))) : h;
    }
    __syncthreads();
    unsigned short* dst = (pass ? Zl : Zh) + ((size_t)(n0 + orow) * 256 + opart * 64);
#pragma unroll
    for (int i = 0; i < 8; ++i)
      *(uint4*)(dst + i * 8) = *(const uint4*)&zt[orow][opart * 64 + i * 8];
  }
}

// numpy pairwise sum of squares, n=256 (two 128-blocks, 8 accumulators)
__device__ __forceinline__ float np_sumsq256(const float* __restrict__ base,
                                             const int stride) {
  float h[2];
#pragma unroll
  for (int half = 0; half < 2; ++half) {
    const float* a = base + (size_t)(half * 128) * stride;
    float r[8];
#pragma unroll
    for (int k = 0; k < 8; ++k) { const float v = a[(size_t)k * stride]; r[k] = __fmul_rn(v, v); }
    for (int i = 8; i < 128; i += 8) {
#pragma unroll
      for (int k = 0; k < 8; ++k) {
        const float v = a[(size_t)(i + k) * stride];
        r[k] = __fadd_rn(r[k], __fmul_rn(v, v));
      }
    }
    h[half] = __fadd_rn(
        __fadd_rn(__fadd_rn(r[0], r[1]), __fadd_rn(r[2], r[3])),
        __fadd_rn(__fadd_rn(r[4], r[5]), __fadd_rn(r[6], r[7])));
  }
  return __fadd_rn(h[0], h[1]);
}

__global__ __launch_bounds__(256) void k_sz(const float* __restrict__ z,
                                            float* __restrict__ S) {
  const int n = blockIdx.x * 256 + threadIdx.x;   // grid 128
  S[n] = np_sumsq256(z + (size_t)(n >> 10) * 262144 + (n & 1023), 1024);
}

__global__ __launch_bounds__(256) void k_wsq(const float* __restrict__ W,
                                             float* __restrict__ B,
                                             unsigned* __restrict__ maxw) {
  const int j = blockIdx.x * 256 + threadIdx.x;   // grid 32
  const float b = np_sumsq256(W + (size_t)j * 256, 1);
  B[j] = b;
  atomicMax(maxw, __float_as_uint(b));
}

// stable merge of two sorted-3 lists (values + indices for top-2)
__device__ __forceinline__ void merge5(float& a1, int& ai1, float& a2, int& ai2,
                                       float& a3, float b1, int bi1, float b2,
                                       int bi2, float b3) {
  const bool t1 = (b1 < a1) || (b1 == a1 && bi1 < ai1);
  const float w2v = t1 ? b2 : a2; const int w2i = t1 ? bi2 : ai2;
  const float w3v = t1 ? b3 : a3;
  const float l1v = t1 ? a1 : b1; const int l1i = t1 ? ai1 : bi1;
  const float l2v = t1 ? a2 : b2;
  const float n1v = t1 ? b1 : a1; const int n1i = t1 ? bi1 : ai1;
  const bool t2 = (w2v < l1v) || (w2v == l1v && w2i < l1i);
  a1 = n1v; ai1 = n1i;
  a2 = t2 ? w2v : l1v; ai2 = t2 ? w2i : l1i;
  a3 = t2 ? fminf(w3v, l1v) : fminf(w2v, l2v);
}

// Coarse pass: C~ = (zh+zl)*wh via 2 MFMAs, d~ = fl(fl(S+B)-2C~), top-3/pixel.
// Block: 512 thr (8 waves), 64 px, A(z) LDS-resident full-K, B dbuf per 32-k chunk.
#define A_STRIDE 272
#define AH_OFF 0
#define AL_OFF 34816
#define B0_OFF 69632
#define B1_OFF 110592
#define SC_OFF 69632
__global__ __launch_bounds__(512, 2) void k_main(
    const unsigned short* __restrict__ Zh, const unsigned short* __restrict__ Zl,
    const unsigned short* __restrict__ Wh, const float* __restrict__ S,
    const float* __restrict__ B, const unsigned* __restrict__ maxw,
    int* __restrict__ idxb, int* __restrict__ cand, int* __restrict__ full,
    int* __restrict__ cnt) {
  extern __shared__ __align__(16) char smem[];
  unsigned short* Ah = (unsigned short*)(smem + AH_OFF);
  unsigned short* Al = (unsigned short*)(smem + AL_OFF);
  const int t = threadIdx.x;
  const int w = t >> 6, lane = t & 63, col = lane & 15, q = lane >> 4;
  const int phalf = w >> 2, strip = w & 3;
  const int n0 = blockIdx.x << 6;             // grid 512

  // ---- stage A (once): 64 rows x 256 k, hi+lo ----
  {
    const int row = t >> 3, seg = t & 7;
    const uint4* sh = (const uint4*)(Zh + (size_t)(n0 + row) * 256 + seg * 32);
    const uint4* sl = (const uint4*)(Zl + (size_t)(n0 + row) * 256 + seg * 32);
    uint4* dh = (uint4*)((char*)Ah + row * (A_STRIDE * 2) + seg * 64);
    uint4* dl = (uint4*)((char*)Al + row * (A_STRIDE * 2) + seg * 64);
#pragma unroll
    for (int i = 0; i < 4; ++i) dh[i] = sh[i];
#pragma unroll
    for (int i = 0; i < 4; ++i) dl[i] = sl[i];
  }
  // ---- B prologue: load (ct=0,kc=0) chunk ----
  uint4 bpre[4];
  {
    const uint4* src = (const uint4*)(Wh + (size_t)t * 256);
#pragma unroll
    for (int i = 0; i < 4; ++i) bpre[i] = src[i];
  }
  __syncthreads();   // A visible
  {
    uint4* dst = (uint4*)(smem + B0_OFF + t * 80);
#pragma unroll
    for (int i = 0; i < 4; ++i) dst[i] = bpre[i];
  }
  __syncthreads();

  float spx[8];
#pragma unroll
  for (int s = 0; s < 8; ++s)
    spx[s] = S[n0 + phalf * 32 + (s >> 2) * 16 + q * 4 + (s & 3)];

  float m1[8], m2[8], m3[8]; int i1[8], i2[8];
#pragma unroll
  for (int s = 0; s < 8; ++s) {
    m1[s] = FLT_MAX; m2[s] = FLT_MAX; m3[s] = FLT_MAX;
    i1[s] = 0x7fffffff; i2[s] = 0x7fffffff;
  }

  v4f acc[2][8];
#pragma unroll
  for (int pt = 0; pt < 2; ++pt)
#pragma unroll
    for (int nt = 0; nt < 8; ++nt) acc[pt][nt] = (v4f){0.f, 0.f, 0.f, 0.f};

  for (int it = 0; it < 128; ++it) {          // 16 ct x 8 kc
    const int ct = it >> 3, kc = it & 7;
    if (it < 127) {                            // prefetch next chunk
      const int nct = (it + 1) >> 3, nkc = (it + 1) & 7;
      const uint4* src = (const uint4*)(Wh + (size_t)(nct * 512 + t) * 256 + nkc * 32);
#pragma unroll
      for (int i = 0; i < 4; ++i) bpre[i] = src[i];
    }
    const char* bbuf = smem + ((it & 1) ? B1_OFF : B0_OFF);
    v8s ah[2], al[2];
#pragma unroll
    for (int pt = 0; pt < 2; ++pt) {
      const int arow = phalf * 32 + pt * 16 + col;
      ah[pt] = *(const v8s*)((const char*)Ah + arow * (A_STRIDE * 2) + kc * 64 + q * 16);
      al[pt] = *(const v8s*)((const char*)Al + arow * (A_STRIDE * 2) + kc * 64 + q * 16);
    }
#pragma unroll
    for (int nt = 0; nt < 8; ++nt) {
      const v8s bh = *(const v8s*)(bbuf + (strip * 128 + nt * 16 + col) * 80 + q * 16);
#pragma unroll
      for (int pt = 0; pt < 2; ++pt) {
        acc[pt][nt] = __builtin_amdgcn_mfma_f32_16x16x32_bf16(ah[pt], bh, acc[pt][nt], 0, 0, 0);
        acc[pt][nt] = __builtin_amdgcn_mfma_f32_16x16x32_bf16(al[pt], bh, acc[pt][nt], 0, 0, 0);
      }
    }
    if (it < 127) {                            // store prefetched into other buf
      uint4* dst = (uint4*)(smem + (((it + 1) & 1) ? B1_OFF : B0_OFF) + t * 80);
#pragma unroll
      for (int i = 0; i < 4; ++i) dst[i] = bpre[i];
    }
    __syncthreads();
    if (kc == 7) {                             // epilogue for this 512-code tile
#pragma unroll
      for (int nt = 0; nt < 8; ++nt) {
        const int code = ct * 512 + strip * 128 + nt * 16 + col;
        const float bb = B[code];
#pragma unroll
        for (int pt = 0; pt < 2; ++pt) {
          const v4f a = acc[pt][nt];
#pragma unroll
          for (int r = 0; r < 4; ++r) {
            const int s = pt * 4 + r;
            const float d = __fsub_rn(__fadd_rn(spx[s], bb), __fmul_rn(2.f, a[r]));
            const bool c1 = (d < m1[s]);
            const bool c2 = (d < m2[s]);
            const bool c3 = (d < m3[s]);
            m3[s] = c2 ? m2[s] : (c3 ? d : m3[s]);
            m2[s] = c1 ? m1[s] : (c2 ? d : m2[s]);
            i2[s] = c1 ? i1[s] : (c2 ? code : i2[s]);
            m1[s] = c1 ? d : m1[s];
            i1[s] = c1 ? code : i1[s];
          }
        }
#pragma unroll
        for (int pt = 0; pt < 2; ++pt) acc[pt][nt] = (v4f){0.f, 0.f, 0.f, 0.f};
      }
    }
  }

  // in-wave merge across the 16 col-lanes
#pragma unroll
  for (int s = 0; s < 8; ++s) {
    for (int msk = 1; msk < 16; msk <<= 1) {
      const float b1 = __shfl_xor(m1[s], msk, 16);
      const int  bi1 = __shfl_xor(i1[s], msk, 16);
      const float b2 = __shfl_xor(m2[s], msk, 16);
      const int  bi2 = __shfl_xor(i2[s], msk, 16);
      const float b3 = __shfl_xor(m3[s], msk, 16);
      merge5(m1[s], i1[s], m2[s], i2[s], m3[s], b1, bi1, b2, bi2, b3);
    }
  }
  __syncthreads();
  float* sc = (float*)(smem + SC_OFF);        // [px][strip][5]
  if (col == 0) {
#pragma unroll
    for (int s = 0; s < 8; ++s) {
      const int px = phalf * 32 + (s >> 2) * 16 + q * 4 + (s & 3);
      const int base = (px * 4 + strip) * 5;
      sc[base]     = m1[s];
      sc[base + 1] = __int_as_float(i1[s]);
      sc[base + 2] = m2[s];
      sc[base + 3] = __int_as_float(i2[s]);
      sc[base + 4] = m3[s];
    }
  }
  __syncthreads();
  if (t < 64) {
    const int base0 = t * 20;
    float A1 = sc[base0], A2 = sc[base0 + 2], A3 = sc[base0 + 4];
    int AI1 = __float_as_int(sc[base0 + 1]), AI2 = __float_as_int(sc[base0 + 3]);
    for (int st = 1; st < 4; ++st) {
      const int base = base0 + st * 5;
      merge5(A1, AI1, A2, AI2, A3, sc[base], __float_as_int(sc[base + 1]),
             sc[base + 2], __float_as_int(sc[base + 3]), sc[base + 4]);
    }
    const int n = n0 + t;
    idxb[n] = AI1;
    // window: 2*(2^-9*||z||*max||w|| + slack) + 2 ulp(m1)
    const float nw = sqrtf(S[n]) * sqrtf(__uint_as_float(*maxw));
    const float win = 2.0f * (0.001953125f * nw + 1e-6f)
                    + 2.0f * ldexpf(1.0f, ilogbf(fmaxf(A1, 1e-30f)) - 23);
    if (A2 <= A1 + win) {
      if (A3 <= A1 + win) {
        const int p = atomicAdd(&cnt[1], 1);
        full[p] = n;
      } else {
        const int p = atomicAdd(&cnt[0], 1);
        cand[3 * p] = n; cand[3 * p + 1] = AI1; cand[3 * p + 2] = AI2;
      }
    }
  }
}

// exact np-chain re-eval of the two candidates
__global__ __launch_bounds__(256) void k_cand(const float* __restrict__ z,
    const float* __restrict__ W, const float* __restrict__ S,
    const float* __restrict__ B, const int* __restrict__ cand,
    const int* __restrict__ cnt, int* __restrict__ idxb) {
  const int e = blockIdx.x * 256 + threadIdx.x;   // grid 128
  if (e >= cnt[0]) return;
  const int n = cand[3 * e], ca = cand[3 * e + 1], cb = cand[3 * e + 2];
  const float* zp = z + (size_t)(n >> 10) * 262144 + (n & 1023);
  const float* wa = W + (size_t)ca * 256;
  const float* wb = W + (size_t)cb * 256;
  float a1 = 0.f, a2 = 0.f;
  for (int c = 0; c < 256; ++c) {
    const float zv = zp[(size_t)c * 1024];
    a1 = __builtin_fmaf(zv, wa[c], a1);
    a2 = __builtin_fmaf(zv, wb[c], a2);
  }
  const float d1 = __fsub_rn(__fadd_rn(S[n], B[ca]), __fmul_rn(2.f, a1));
  const float d2 = __fsub_rn(__fadd_rn(S[n], B[cb]), __fmul_rn(2.f, a2));
  idxb[n] = (d1 < d2) ? ca : ((d2 < d1) ? cb : min(ca, cb));
}

// Exact full argmin, round-3-GEMM style. Unit = (32-px group, 1024-code slice).
// z full-K in LDS; W chunks LDS-transposed (pad 257 -> ~2-way banks); exact
// single-acc fmaf chain; per-px slice-min -> atomicMin packed (d_bits<<13|j).
__global__ __launch_bounds__(256) void k_full(const float* __restrict__ z,
    const float* __restrict__ W, const float* __restrict__ S,
    const float* __restrict__ B, const int* __restrict__ full,
    const int* __restrict__ cnt, unsigned long long* __restrict__ fkey) {
  extern __shared__ __align__(16) char fsm[];
  float* zsf = (float*)fsm;                    // [256][32]
  float* wt  = (float*)(fsm + 32768);          // [32][257]
  float* mv  = (float*)(fsm + 32768 + 32896);  // [32][33]
  int*   mi  = (int*)(fsm + 32768 + 32896 + 4224);
  const int t = threadIdx.x;
  const int pg = t & 7, cg = t >> 3;
  const int fN = min(cnt[1], 32768);
  const int units = ((fN + 31) >> 5) << 3;
  for (int e = blockIdx.x; e < units; e += 2048) {
    const int g = e >> 3, s = e & 7;
    __syncthreads();                           // LDS reuse guard
    {                                          // stage z full-K for 32 px
      const int slot = t & 31, part = t >> 5;
      const int f = (g << 5) + slot;
      const int n = (f < fN) ? full[f] : full[0];
      const float* zp = z + (size_t)(n >> 10) * 262144 + (n & 1023);
      for (int i = 0; i < 32; ++i) {
        const int k = (part << 5) + i;
        zsf[k * 32 + slot] = zp[(size_t)k * 1024];
      }
    }
    float s4[4]; bool va[4];
#pragma unroll
    for (int i = 0; i < 4; ++i) {
      const int f = (g << 5) + (pg << 2) + i;
      va[i] = f < fN;
      s4[i] = va[i] ? S[full[f]] : 0.f;
    }
    float bm[4]; int bj[4];
#pragma unroll
    for (int i = 0; i < 4; ++i) { bm[i] = FLT_MAX; bj[i] = 0x7fffffff; }
    float acc[4][8];
    for (int tile = 0; tile < 4; ++tile) {
      const int c0 = (s << 10) + (tile << 8);
#pragma unroll
      for (int i = 0; i < 4; ++i)
#pragma unroll
        for (int u = 0; u < 8; ++u) acc[i][u] = 0.f;
      for (int kc = 0; kc < 8; ++kc) {
        const int kb = kc << 5;
        __syncthreads();
#pragma unroll
        for (int p = 0; p < 8; ++p) {          // W chunk, transposed store
          const int jl = (t >> 3) + (p << 5);
          const float4 wv4 =
              *(const float4*)&W[(size_t)(c0 + jl) * 256 + kb + ((t & 7) << 2)];
          const int k0 = (t & 7) << 2;
          wt[(k0    ) * 257 + jl] = wv4.x;
          wt[(k0 + 1) * 257 + jl] = wv4.y;
          wt[(k0 + 2) * 257 + jl] = wv4.z;
          wt[(k0 + 3) * 257 + jl] = wv4.w;
        }
        __syncthreads();
        for (int k = 0; k < 32; ++k) {
          const float4 z4 = *(const float4*)&zsf[(kb + k) * 32 + (pg << 2)];
          const float4 wA = *(const float4*)&wt[k * 257 + (cg << 3)];
          const float4 wB = *(const float4*)&wt[k * 257 + (cg << 3) + 4];
          const float zv[4] = {z4.x, z4.y, z4.z, z4.w};
          const float wv[8] = {wA.x, wA.y, wA.z, wA.w, wB.x, wB.y, wB.z, wB.w};
#pragma unroll
          for (int i = 0; i < 4; ++i)
#pragma unroll
            for (int u = 0; u < 8; ++u)
              acc[i][u] = __builtin_fmaf(zv[i], wv[u], acc[i][u]);
        }
      }
#pragma unroll
      for (int u = 0; u < 8; ++u) {            // tile epilogue
        const int code = c0 + (cg << 3) + u;
        const float bb = B[code];
#pragma unroll
        for (int i = 0; i < 4; ++i) {
          const float d = __fsub_rn(__fadd_rn(s4[i], bb), __fmul_rn(2.f, acc[i][u]));
          if (d < bm[i]) { bm[i] = d; bj[i] = code; }
        }
      }
    }
    __syncthreads();                           // merge across cg
#pragma unroll
    for (int i = 0; i < 4; ++i) {
      const int px = (pg << 2) + i;
      mv[px * 33 + cg] = bm[i];
      mi[px * 33 + cg] = bj[i];
    }
    __syncthreads();
    if (t < 32) {
      float m = mv[t * 33]; int j = mi[t * 33];
      for (int c = 1; c < 32; ++c) {
        const float v = mv[t * 33 + c]; const int vi = mi[t * 33 + c];
        if (v < m || (v == m && vi < j)) { m = v; j = vi; }
      }
      const int f = (g << 5) + t;
      if (f < fN) {
        const unsigned long long key =
            (((unsigned long long)__float_as_uint(m)) << 13) | (unsigned)j;
        atomicMin(&fkey[f], key);
      }
    }
  }
}

__global__ __launch_bounds__(256) void k_fullfin(const int* __restrict__ full,
    const int* __restrict__ cnt, const unsigned long long* __restrict__ fkey,
    int* __restrict__ idxb) {
  const int f = blockIdx.x * 256 + threadIdx.x;   // grid 128
  if (f < cnt[1]) idxb[full[f]] = (int)(fkey[f] & 8191ull);
}

// z_q gather (STE rounding) + loss + histogram + index output
__global__ __launch_bounds__(256) void k_zq(const float* __restrict__ z,
    const float* __restrict__ W, const int* __restrict__ idxb,
    float* __restrict__ out, double* __restrict__ loss, int* __restrict__ hist) {
  __shared__ float red[256];
  const int t = threadIdx.x;
  const int tx = t & 63, ty = t >> 6;
  const int n0 = blockIdx.x << 6;            // grid 512
  const int n = n0 + tx;
  const int b = n >> 10;
  const int p = n & 1023;
  const int myidx = idxb[n];
  const float* wrow = W + (size_t)myidx * 256;
  float lsum = 0.f;
#pragma unroll 4
  for (int cc = 0; cc < 64; ++cc) {
    const int c = ty * 64 + cc;
    const float qv = wrow[c];
    const size_t off = (size_t)b * 262144 + (size_t)c * 1024 + p;
    const float zv = z[off];
    const float d = __fsub_rn(qv, zv);
    lsum = __builtin_fmaf(d, d, lsum);
    out[off] = __fadd_rn(zv, d);
  }
  red[t] = lsum;
  __syncthreads();
  for (int o = 128; o > 0; o >>= 1) {
    if (t < o) red[t] += red[t + o];
    __syncthreads();
  }
  if (t == 0) atomicAdd(loss, (double)red[0]);
  if (ty == 0) atomicAdd(&hist[myidx], 1);
  if (ty == 1) out[OUT_IDX + n] = (float)myidx;
}

__global__ void k_final(const int* __restrict__ hist,
                        const double* __restrict__ loss,
                        float* __restrict__ out) {
  __shared__ double sh[256];
  const int t = threadIdx.x;
  double s = 0.0;
  for (int j = t; j < 8192; j += 256) {
    const double e = (double)hist[j] / 32768.0;
    s += e * log(e + 1e-10);
  }
  sh[t] = s;
  __syncthreads();
  for (int off = 128; off > 0; off >>= 1) {
    if (t < off) sh[t] += sh[t + off];
    __syncthreads();
  }
  if (t == 0) {
    out[OUT_PERP] = (float)exp(-sh[0]);
    out[OUT_LOSS] = (float)(1.25 * (*loss) / 8388608.0);
  }
}

extern "C" void kernel_launch(void* const* d_in, const int* in_sizes, int n_in,
                              void* d_out, int out_size, void* d_ws, size_t ws_size,
                              hipStream_t stream) {
  const float* z = (const float*)d_in[0];
  const float* W = (const float*)d_in[1];
  float* out = (float*)d_out;
  char* ws = (char*)d_ws;
  unsigned short* Zh = (unsigned short*)(ws + WS_ZH);
  unsigned short* Zl = (unsigned short*)(ws + WS_ZL);
  unsigned short* Wh = (unsigned short*)(ws + WS_WH);
  float*  S    = (float*)(ws + WS_S);
  float*  B    = (float*)(ws + WS_B);
  unsigned* maxw = (unsigned*)(ws + WS_MAXW);
  int*    idxb = (int*)(ws + WS_IDX);
  int*    hist = (int*)(ws + WS_HIST);
  int*    cand = (int*)(ws + WS_CAND);
  int*    full = (int*)(ws + WS_FULL);
  unsigned long long* fkey = (unsigned long long*)(ws + WS_FKEY);
  int*    cnt  = (int*)(ws + WS_CNT);
  double* loss = (double*)(ws + WS_LOSS);

  hipLaunchKernelGGL(k_zero,    dim3(161),  dim3(256), 0, stream, hist, fkey, cnt, loss, maxw);
  hipLaunchKernelGGL(k_split,   dim3(2048), dim3(256), 0, stream, W, Wh);
  hipLaunchKernelGGL(k_splitz,  dim3(512),  dim3(256), 0, stream, z, Zh, Zl);
  hipLaunchKernelGGL(k_sz,      dim3(128),  dim3(256), 0, stream, z, S);
  hipLaunchKernelGGL(k_wsq,     dim3(32),   dim3(256), 0, stream, W, B, maxw);
  hipLaunchKernelGGL(k_main,    dim3(512),  dim3(512), 151552, stream,
                     Zh, Zl, Wh, S, B, maxw, idxb, cand, full, cnt);
  hipLaunchKernelGGL(k_cand,    dim3(128),  dim3(256), 0, stream, z, W, S, B, cand, cnt, idxb);
  hipLaunchKernelGGL(k_full,    dim3(2048), dim3(256), 74112, stream, z, W, S, B, full, cnt, fkey);
  hipLaunchKernelGGL(k_fullfin, dim3(128),  dim3(256), 0, stream, full, cnt, fkey, idxb);
  hipLaunchKernelGGL(k_zq,      dim3(512),  dim3(256), 0, stream, z, W, idxb, out, loss, hist);
  hipLaunchKernelGGL(k_final,   dim3(1),    dim3(256), 0, stream, hist, loss, out);
}

// Round 7
// 1403.571 us; speedup vs baseline: 4.8690x; 1.0658x over previous
//
#include <hip/hip_runtime.h>
#include <float.h>
#include <math.h>

// Problem: z (32,256,32,32) f32, W (8192,256) f32.
// Outputs flat: z_q [0,8388608) | loss [8388608] | index [8388609,8421377) | perp [8421377]
#define OUT_LOSS 8388608
#define OUT_IDX  8388609
#define OUT_PERP 8421377

// Workspace layout (bytes)  (~38.9 MB total)
// Blocked layouts: X[kc][n][32k] with kc = k>>5 (32-k chunks) for coalesced
// staging + conflict-free LDS in k_main.
#define WS_ZH    0ull          // ushort[8][32768][32]  bf16 hi of z
#define WS_ZL    16777216ull   // ushort[8][32768][32]  bf16 lo of z
#define WS_WH    33554432ull   // ushort[8][8192][32]   bf16 hi of W
#define WS_S     37748736ull   // float[32768]  ||z||^2 np-pairwise
#define WS_B     37879808ull   // float[8192]   ||W||^2 np-pairwise
#define WS_MAXW  37912576ull   // uint           max_j B_j (bits)
#define WS_IDX   37912640ull   // int[32768]
#define WS_HIST  38043712ull   // int[8192]
#define WS_CAND  38076480ull   // int[3*32768]
#define WS_FULL  38469696ull   // int[32768]
#define WS_FKEY  38600768ull   // u64[32768]
#define WS_CNT   38862912ull   // int[2]
#define WS_LOSS  38862920ull   // double

typedef short v8s __attribute__((ext_vector_type(8)));
typedef float v4f __attribute__((ext_vector_type(4)));

__device__ __forceinline__ unsigned short bf16rne(float f) {
  unsigned u = __float_as_uint(f);
  return (unsigned short)((u + 0x7FFFu + ((u >> 16) & 1u)) >> 16);
}
__device__ __forceinline__ float bf16tof(unsigned short h) {
  return __uint_as_float(((unsigned)h) << 16);
}

__global__ void k_zero(int* __restrict__ hist, unsigned long long* __restrict__ fkey,
                       int* __restrict__ cnt, double* __restrict__ loss,
                       unsigned* __restrict__ maxw) {
  const int i = blockIdx.x * 256 + threadIdx.x;   // grid 161
  if (i < 8192) hist[i] = 0;
  else if (i < 40960) fkey[i - 8192] = ~0ull;
  else if (i == 40960) cnt[0] = 0;
  else if (i == 40961) cnt[1] = 0;
  else if (i == 40962) *loss = 0.0;
  else if (i == 40963) *maxw = 0u;
}

// W -> bf16 hi, blocked layout Wh[k>>5][j][k&31]
__global__ __launch_bounds__(256) void k_split(const float* __restrict__ W,
                                               unsigned short* __restrict__ Wh) {
  const int o4 = (blockIdx.x * 256 + threadIdx.x) * 4;   // grid 2048
  const int j = o4 >> 8, k = o4 & 255;
  const float4 w = *(const float4*)(W + o4);
  const float wv[4] = {w.x, w.y, w.z, w.w};
  ushort4 h;
  unsigned short* hp = (unsigned short*)&h;
#pragma unroll
  for (int i = 0; i < 4; ++i) hp[i] = bf16rne(wv[i]);
  *(ushort4*)(Wh + ((size_t)(k >> 5) * 8192 + j) * 32 + (k & 31)) = h;
}

// z (32,256,32,32) -> Zh/Zl[kc][n][32] bf16 (n = b*1024 + p). No LDS needed:
// reads are lane-coalesced (fixed c, consecutive p), writes contiguous 64 B.
__global__ __launch_bounds__(256) void k_splitz(const float* __restrict__ z,
    unsigned short* __restrict__ Zh, unsigned short* __restrict__ Zl) {
  const int gt = blockIdx.x * 256 + threadIdx.x;   // grid 1024
  const int kc = gt >> 15;
  const int n  = gt & 32767;
  const int b = n >> 10, p = n & 1023;
  const float* zp = z + (size_t)b * 262144 + (size_t)(kc * 32) * 1024 + p;
  unsigned short hh[32], ll[32];
#pragma unroll
  for (int i = 0; i < 32; ++i) {
    const float v = zp[(size_t)i * 1024];
    const unsigned short h = bf16rne(v);
    hh[i] = h;
    ll[i] = bf16rne(__fsub_rn(v, bf16tof(h)));
  }
  const size_t o = ((size_t)kc * 32768 + n) * 32;
#pragma unroll
  for (int i = 0; i < 4; ++i) *(uint4*)(Zh + o + i * 8) = *(const uint4*)(hh + i * 8);
#pragma unroll
  for (int i = 0; i < 4; ++i) *(uint4*)(Zl + o + i * 8) = *(const uint4*)(ll + i * 8);
}

// numpy pairwise sum of squares, n=256 (two 128-blocks, 8 accumulators)
__device__ __forceinline__ float np_sumsq256(const float* __restrict__ base,
                                             const int stride) {
  float h[2];
#pragma unroll
  for (int half = 0; half < 2; ++half) {
    const float* a = base + (size_t)(half * 128) * stride;
    float r[8];
#pragma unroll
    for (int k = 0; k < 8; ++k) { const float v = a[(size_t)k * stride]; r[k] = __fmul_rn(v, v); }
    for (int i = 8; i < 128; i += 8) {
#pragma unroll
      for (int k = 0; k < 8; ++k) {
        const float v = a[(size_t)(i + k) * stride];
        r[k] = __fadd_rn(r[k], __fmul_rn(v, v));
      }
    }
    h[half] = __fadd_rn(
        __fadd_rn(__fadd_rn(r[0], r[1]), __fadd_rn(r[2], r[3])),
        __fadd_rn(__fadd_rn(r[4], r[5]), __fadd_rn(r[6], r[7])));
  }
  return __fadd_rn(h[0], h[1]);
}

__global__ __launch_bounds__(256) void k_sz(const float* __restrict__ z,
                                            float* __restrict__ S) {
  const int n = blockIdx.x * 256 + threadIdx.x;   // grid 128
  S[n] = np_sumsq256(z + (size_t)(n >> 10) * 262144 + (n & 1023), 1024);
}

__global__ __launch_bounds__(256) void k_wsq(const float* __restrict__ W,
                                             float* __restrict__ B,
                                             unsigned* __restrict__ maxw) {
  const int j = blockIdx.x * 256 + threadIdx.x;   // grid 32
  const float b = np_sumsq256(W + (size_t)j * 256, 1);
  B[j] = b;
  atomicMax(maxw, __float_as_uint(b));
}

// stable merge of two sorted-3 lists (values + indices for top-2)
__device__ __forceinline__ void merge5(float& a1, int& ai1, float& a2, int& ai2,
                                       float& a3, float b1, int bi1, float b2,
                                       int bi2, float b3) {
  const bool t1 = (b1 < a1) || (b1 == a1 && bi1 < ai1);
  const float w2v = t1 ? b2 : a2; const int w2i = t1 ? bi2 : ai2;
  const float w3v = t1 ? b3 : a3;
  const float l1v = t1 ? a1 : b1; const int l1i = t1 ? ai1 : bi1;
  const float l2v = t1 ? a2 : b2;
  const float n1v = t1 ? b1 : a1; const int n1i = t1 ? bi1 : ai1;
  const bool t2 = (w2v < l1v) || (w2v == l1v && w2i < l1i);
  a1 = n1v; ai1 = n1i;
  a2 = t2 ? w2v : l1v; ai2 = t2 ? w2i : l1i;
  a3 = t2 ? fminf(w3v, l1v) : fminf(w2v, l2v);
}

// Coarse pass: C~ = (zh+zl)*wh via 2 MFMAs, d~ = fl(fl(S+B)-2C~), top-3/pixel.
// Conflict-free LDS: A[kc][row][64B], B[row][64B] -> all fragment reads/stores
// are contiguous 1KB-per-wave b128 patterns; staging is contiguous block copy.
#define AH_OFF 0        // 32 KB
#define AL_OFF 32768    // 32 KB
#define B0_OFF 65536    // 32 KB
#define B1_OFF 98304    // 32 KB
#define SC_OFF 65536    // merge scratch (reuses B0 after main loop)
__global__ __launch_bounds__(512, 2) void k_main(
    const unsigned short* __restrict__ Zh, const unsigned short* __restrict__ Zl,
    const unsigned short* __restrict__ Wh, const float* __restrict__ S,
    const float* __restrict__ B, const unsigned* __restrict__ maxw,
    int* __restrict__ idxb, int* __restrict__ cand, int* __restrict__ full,
    int* __restrict__ cnt) {
  extern __shared__ __align__(16) char smem[];
  const int t = threadIdx.x;
  const int w = t >> 6, lane = t & 63, col = lane & 15, q = lane >> 4;
  const int phalf = w >> 2, strip = w & 3;
  const int n0 = blockIdx.x << 6;             // grid 512

  // ---- stage A (once): [kc][64 rows][32k], hi+lo; contiguous copy ----
  {
    const int kc = t >> 6, row = t & 63;
    const uint4* sh = (const uint4*)(Zh + ((size_t)kc * 32768 + n0 + row) * 32);
    const uint4* sl = (const uint4*)(Zl + ((size_t)kc * 32768 + n0 + row) * 32);
    uint4* dh = (uint4*)(smem + AH_OFF + kc * 4096 + row * 64);
    uint4* dl = (uint4*)(smem + AL_OFF + kc * 4096 + row * 64);
#pragma unroll
    for (int i = 0; i < 4; ++i) dh[i] = sh[i];
#pragma unroll
    for (int i = 0; i < 4; ++i) dl[i] = sl[i];
  }
  // ---- B prologue: chunk (ct=0,kc=0) = contiguous 32 KB ----
  uint4 bpre[4];
  {
    const uint4* src = (const uint4*)(Wh + (size_t)t * 32);
#pragma unroll
    for (int i = 0; i < 4; ++i) bpre[i] = src[i];
  }
  __syncthreads();   // A visible
  {
    uint4* dst = (uint4*)(smem + B0_OFF + t * 64);
#pragma unroll
    for (int i = 0; i < 4; ++i) dst[i] = bpre[i];
  }
  __syncthreads();

  float spx[8];
#pragma unroll
  for (int s = 0; s < 8; ++s)
    spx[s] = S[n0 + phalf * 32 + (s >> 2) * 16 + q * 4 + (s & 3)];

  float m1[8], m2[8], m3[8]; int i1[8], i2[8];
#pragma unroll
  for (int s = 0; s < 8; ++s) {
    m1[s] = FLT_MAX; m2[s] = FLT_MAX; m3[s] = FLT_MAX;
    i1[s] = 0x7fffffff; i2[s] = 0x7fffffff;
  }

  v4f acc[2][8];
#pragma unroll
  for (int pt = 0; pt < 2; ++pt)
#pragma unroll
    for (int nt = 0; nt < 8; ++nt) acc[pt][nt] = (v4f){0.f, 0.f, 0.f, 0.f};

  for (int it = 0; it < 128; ++it) {          // 16 ct x 8 kc
    const int ct = it >> 3, kc = it & 7;
    if (it < 127) {                            // prefetch next chunk (coalesced)
      const int nct = (it + 1) >> 3, nkc = (it + 1) & 7;
      const uint4* src =
          (const uint4*)(Wh + ((size_t)nkc * 8192 + nct * 512 + t) * 32);
#pragma unroll
      for (int i = 0; i < 4; ++i) bpre[i] = src[i];
    }
    const char* bbuf = smem + ((it & 1) ? B1_OFF : B0_OFF);
    v8s ah[2], al[2];
#pragma unroll
    for (int pt = 0; pt < 2; ++pt) {
      const int arow = phalf * 32 + pt * 16 + col;
      ah[pt] = *(const v8s*)(smem + AH_OFF + kc * 4096 + arow * 64 + q * 16);
      al[pt] = *(const v8s*)(smem + AL_OFF + kc * 4096 + arow * 64 + q * 16);
    }
#pragma unroll
    for (int nt = 0; nt < 8; ++nt) {
      const v8s bh = *(const v8s*)(bbuf + (strip * 128 + nt * 16 + col) * 64 + q * 16);
#pragma unroll
      for (int pt = 0; pt < 2; ++pt) {
        acc[pt][nt] = __builtin_amdgcn_mfma_f32_16x16x32_bf16(ah[pt], bh, acc[pt][nt], 0, 0, 0);
        acc[pt][nt] = __builtin_amdgcn_mfma_f32_16x16x32_bf16(al[pt], bh, acc[pt][nt], 0, 0, 0);
      }
    }
    if (it < 127) {                            // store prefetched into other buf
      uint4* dst = (uint4*)(smem + (((it + 1) & 1) ? B1_OFF : B0_OFF) + t * 64);
#pragma unroll
      for (int i = 0; i < 4; ++i) dst[i] = bpre[i];
    }
    __syncthreads();
    if (kc == 7) {                             // epilogue for this 512-code tile
#pragma unroll
      for (int nt = 0; nt < 8; ++nt) {
        const int code = ct * 512 + strip * 128 + nt * 16 + col;
        const float bb = B[code];
#pragma unroll
        for (int pt = 0; pt < 2; ++pt) {
          const v4f a = acc[pt][nt];
#pragma unroll
          for (int r = 0; r < 4; ++r) {
            const int s = pt * 4 + r;
            const float d = __fsub_rn(__fadd_rn(spx[s], bb), __fmul_rn(2.f, a[r]));
            const bool c1 = (d < m1[s]);
            const bool c2 = (d < m2[s]);
            const bool c3 = (d < m3[s]);
            m3[s] = c2 ? m2[s] : (c3 ? d : m3[s]);
            m2[s] = c1 ? m1[s] : (c2 ? d : m2[s]);
            i2[s] = c1 ? i1[s] : (c2 ? code : i2[s]);
            m1[s] = c1 ? d : m1[s];
            i1[s] = c1 ? code : i1[s];
          }
        }
#pragma unroll
        for (int pt = 0; pt < 2; ++pt) acc[pt][nt] = (v4f){0.f, 0.f, 0.f, 0.f};
      }
    }
  }

  // in-wave merge across the 16 col-lanes
#pragma unroll
  for (int s = 0; s < 8; ++s) {
    for (int msk = 1; msk < 16; msk <<= 1) {
      const float b1 = __shfl_xor(m1[s], msk, 16);
      const int  bi1 = __shfl_xor(i1[s], msk, 16);
      const float b2 = __shfl_xor(m2[s], msk, 16);
      const int  bi2 = __shfl_xor(i2[s], msk, 16);
      const float b3 = __shfl_xor(m3[s], msk, 16);
      merge5(m1[s], i1[s], m2[s], i2[s], m3[s], b1, bi1, b2, bi2, b3);
    }
  }
  __syncthreads();
  float* sc = (float*)(smem + SC_OFF);        // [px][strip][5]
  if (col == 0) {
#pragma unroll
    for (int s = 0; s < 8; ++s) {
      const int px = phalf * 32 + (s >> 2) * 16 + q * 4 + (s & 3);
      const int base = (px * 4 + strip) * 5;
      sc[base]     = m1[s];
      sc[base + 1] = __int_as_float(i1[s]);
      sc[base + 2] = m2[s];
      sc[base + 3] = __int_as_float(i2[s]);
      sc[base + 4] = m3[s];
    }
  }
  __syncthreads();
  if (t < 64) {
    const int base0 = t * 20;
    float A1 = sc[base0], A2 = sc[base0 + 2], A3 = sc[base0 + 4];
    int AI1 = __float_as_int(sc[base0 + 1]), AI2 = __float_as_int(sc[base0 + 3]);
    for (int st = 1; st < 4; ++st) {
      const int base = base0 + st * 5;
      merge5(A1, AI1, A2, AI2, A3, sc[base], __float_as_int(sc[base + 1]),
             sc[base + 2], __float_as_int(sc[base + 3]), sc[base + 4]);
    }
    const int n = n0 + t;
    idxb[n] = AI1;
    // window: 2*(2^-9*||z||*max||w|| + slack) + 2 ulp(m1)
    const float nw = sqrtf(S[n]) * sqrtf(__uint_as_float(*maxw));
    const float win = 2.0f * (0.001953125f * nw + 1e-6f)
                    + 2.0f * ldexpf(1.0f, ilogbf(fmaxf(A1, 1e-30f)) - 23);
    if (A2 <= A1 + win) {
      if (A3 <= A1 + win) {
        const int p = atomicAdd(&cnt[1], 1);
        full[p] = n;
      } else {
        const int p = atomicAdd(&cnt[0], 1);
        cand[3 * p] = n; cand[3 * p + 1] = AI1; cand[3 * p + 2] = AI2;
      }
    }
  }
}

// exact np-chain re-eval of the two candidates
__global__ __launch_bounds__(256) void k_cand(const float* __restrict__ z,
    const float* __restrict__ W, const float* __restrict__ S,
    const float* __restrict__ B, const int* __restrict__ cand,
    const int* __restrict__ cnt, int* __restrict__ idxb) {
  const int e = blockIdx.x * 256 + threadIdx.x;   // grid 128
  if (e >= cnt[0]) return;
  const int n = cand[3 * e], ca = cand[3 * e + 1], cb = cand[3 * e + 2];
  const float* zp = z + (size_t)(n >> 10) * 262144 + (n & 1023);
  const float* wa = W + (size_t)ca * 256;
  const float* wb = W + (size_t)cb * 256;
  float a1 = 0.f, a2 = 0.f;
  for (int c = 0; c < 256; ++c) {
    const float zv = zp[(size_t)c * 1024];
    a1 = __builtin_fmaf(zv, wa[c], a1);
    a2 = __builtin_fmaf(zv, wb[c], a2);
  }
  const float d1 = __fsub_rn(__fadd_rn(S[n], B[ca]), __fmul_rn(2.f, a1));
  const float d2 = __fsub_rn(__fadd_rn(S[n], B[cb]), __fmul_rn(2.f, a2));
  idxb[n] = (d1 < d2) ? ca : ((d2 < d1) ? cb : min(ca, cb));
}

// Exact full argmin, round-3-GEMM style. Unit = (32-px group, 1024-code slice).
__global__ __launch_bounds__(256) void k_full(const float* __restrict__ z,
    const float* __restrict__ W, const float* __restrict__ S,
    const float* __restrict__ B, const int* __restrict__ full,
    const int* __restrict__ cnt, unsigned long long* __restrict__ fkey) {
  extern __shared__ __align__(16) char fsm[];
  float* zsf = (float*)fsm;                    // [256][32]
  float* wt  = (float*)(fsm + 32768);          // [32][257]
  float* mv  = (float*)(fsm + 32768 + 32896);  // [32][33]
  int*   mi  = (int*)(fsm + 32768 + 32896 + 4224);
  const int t = threadIdx.x;
  const int pg = t & 7, cg = t >> 3;
  const int fN = min(cnt[1], 32768);
  const int units = ((fN + 31) >> 5) << 3;
  for (int e = blockIdx.x; e < units; e += 2048) {
    const int g = e >> 3, s = e & 7;
    __syncthreads();                           // LDS reuse guard
    {                                          // stage z full-K for 32 px
      const int slot = t & 31, part = t >> 5;
      const int f = (g << 5) + slot;
      const int n = (f < fN) ? full[f] : full[0];
      const float* zp = z + (size_t)(n >> 10) * 262144 + (n & 1023);
      for (int i = 0; i < 32; ++i) {
        const int k = (part << 5) + i;
        zsf[k * 32 + slot] = zp[(size_t)k * 1024];
      }
    }
    float s4[4];
#pragma unroll
    for (int i = 0; i < 4; ++i) {
      const int f = (g << 5) + (pg << 2) + i;
      s4[i] = (f < fN) ? S[full[f]] : 0.f;
    }
    float bm[4]; int bj[4];
#pragma unroll
    for (int i = 0; i < 4; ++i) { bm[i] = FLT_MAX; bj[i] = 0x7fffffff; }
    float acc[4][8];
    for (int tile = 0; tile < 4; ++tile) {
      const int c0 = (s << 10) + (tile << 8);
#pragma unroll
      for (int i = 0; i < 4; ++i)
#pragma unroll
        for (int u = 0; u < 8; ++u) acc[i][u] = 0.f;
      for (int kc = 0; kc < 8; ++kc) {
        const int kb = kc << 5;
        __syncthreads();
#pragma unroll
        for (int p = 0; p < 8; ++p) {          // W chunk, transposed store
          const int jl = (t >> 3) + (p << 5);
          const float4 wv4 =
              *(const float4*)&W[(size_t)(c0 + jl) * 256 + kb + ((t & 7) << 2)];
          const int k0 = (t & 7) << 2;
          wt[(k0    ) * 257 + jl] = wv4.x;
          wt[(k0 + 1) * 257 + jl] = wv4.y;
          wt[(k0 + 2) * 257 + jl] = wv4.z;
          wt[(k0 + 3) * 257 + jl] = wv4.w;
        }
        __syncthreads();
        for (int k = 0; k < 32; ++k) {
          const float4 z4 = *(const float4*)&zsf[(kb + k) * 32 + (pg << 2)];
          const float4 wA = *(const float4*)&wt[k * 257 + (cg << 3)];
          const float4 wB = *(const float4*)&wt[k * 257 + (cg << 3) + 4];
          const float zv[4] = {z4.x, z4.y, z4.z, z4.w};
          const float wv[8] = {wA.x, wA.y, wA.z, wA.w, wB.x, wB.y, wB.z, wB.w};
#pragma unroll
          for (int i = 0; i < 4; ++i)
#pragma unroll
            for (int u = 0; u < 8; ++u)
              acc[i][u] = __builtin_fmaf(zv[i], wv[u], acc[i][u]);
        }
      }
#pragma unroll
      for (int u = 0; u < 8; ++u) {            // tile epilogue
        const int code = c0 + (cg << 3) + u;
        const float bb = B[code];
#pragma unroll
        for (int i = 0; i < 4; ++i) {
          const float d = __fsub_rn(__fadd_rn(s4[i], bb), __fmul_rn(2.f, acc[i][u]));
          if (d < bm[i]) { bm[i] = d; bj[i] = code; }
        }
      }
    }
    __syncthreads();                           // merge across cg
#pragma unroll
    for (int i = 0; i < 4; ++i) {
      const int px = (pg << 2) + i;
      mv[px * 33 + cg] = bm[i];
      mi[px * 33 + cg] = bj[i];
    }
    __syncthreads();
    if (t < 32) {
      float m = mv[t * 33]; int j = mi[t * 33];
      for (int c = 1; c < 32; ++c) {
        const float v = mv[t * 33 + c]; const int vi = mi[t * 33 + c];
        if (v < m || (v == m && vi < j)) { m = v; j = vi; }
      }
      const int f = (g << 5) + t;
      if (f < fN) {
        const unsigned long long key =
            (((unsigned long long)__float_as_uint(m)) << 13) | (unsigned)j;
        atomicMin(&fkey[f], key);
      }
    }
  }
}

__global__ __launch_bounds__(256) void k_fullfin(const int* __restrict__ full,
    const int* __restrict__ cnt, const unsigned long long* __restrict__ fkey,
    int* __restrict__ idxb) {
  const int f = blockIdx.x * 256 + threadIdx.x;   // grid 128
  if (f < cnt[1]) idxb[full[f]] = (int)(fkey[f] & 8191ull);
}

// z_q gather (STE rounding) + loss + histogram + index output
__global__ __launch_bounds__(256) void k_zq(const float* __restrict__ z,
    const float* __restrict__ W, const int* __restrict__ idxb,
    float* __restrict__ out, double* __restrict__ loss, int* __restrict__ hist) {
  __shared__ float red[256];
  const int t = threadIdx.x;
  const int tx = t & 63, ty = t >> 6;
  const int n0 = blockIdx.x << 6;            // grid 512
  const int n = n0 + tx;
  const int b = n >> 10;
  const int p = n & 1023;
  const int myidx = idxb[n];
  const float* wrow = W + (size_t)myidx * 256;
  float lsum = 0.f;
#pragma unroll 4
  for (int cc = 0; cc < 64; ++cc) {
    const int c = ty * 64 + cc;
    const float qv = wrow[c];
    const size_t off = (size_t)b * 262144 + (size_t)c * 1024 + p;
    const float zv = z[off];
    const float d = __fsub_rn(qv, zv);
    lsum = __builtin_fmaf(d, d, lsum);
    out[off] = __fadd_rn(zv, d);
  }
  red[t] = lsum;
  __syncthreads();
  for (int o = 128; o > 0; o >>= 1) {
    if (t < o) red[t] += red[t + o];
    __syncthreads();
  }
  if (t == 0) atomicAdd(loss, (double)red[0]);
  if (ty == 0) atomicAdd(&hist[myidx], 1);
  if (ty == 1) out[OUT_IDX + n] = (float)myidx;
}

__global__ void k_final(const int* __restrict__ hist,
                        const double* __restrict__ loss,
                        float* __restrict__ out) {
  __shared__ double sh[256];
  const int t = threadIdx.x;
  double s = 0.0;
  for (int j = t; j < 8192; j += 256) {
    const double e = (double)hist[j] / 32768.0;
    s += e * log(e + 1e-10);
  }
  sh[t] = s;
  __syncthreads();
  for (int off = 128; off > 0; off >>= 1) {
    if (t < off) sh[t] += sh[t + off];
    __syncthreads();
  }
  if (t == 0) {
    out[OUT_PERP] = (float)exp(-sh[0]);
    out[OUT_LOSS] = (float)(1.25 * (*loss) / 8388608.0);
  }
}

extern "C" void kernel_launch(void* const* d_in, const int* in_sizes, int n_in,
                              void* d_out, int out_size, void* d_ws, size_t ws_size,
                              hipStream_t stream) {
  const float* z = (const float*)d_in[0];
  const float* W = (const float*)d_in[1];
  float* out = (float*)d_out;
  char* ws = (char*)d_ws;
  unsigned short* Zh = (unsigned short*)(ws + WS_ZH);
  unsigned short* Zl = (unsigned short*)(ws + WS_ZL);
  unsigned short* Wh = (unsigned short*)(ws + WS_WH);
  float*  S    = (float*)(ws + WS_S);
  float*  B    = (float*)(ws + WS_B);
  unsigned* maxw = (unsigned*)(ws + WS_MAXW);
  int*    idxb = (int*)(ws + WS_IDX);
  int*    hist = (int*)(ws + WS_HIST);
  int*    cand = (int*)(ws + WS_CAND);
  int*    full = (int*)(ws + WS_FULL);
  unsigned long long* fkey = (unsigned long long*)(ws + WS_FKEY);
  int*    cnt  = (int*)(ws + WS_CNT);
  double* loss = (double*)(ws + WS_LOSS);

  hipLaunchKernelGGL(k_zero,    dim3(161),  dim3(256), 0, stream, hist, fkey, cnt, loss, maxw);
  hipLaunchKernelGGL(k_split,   dim3(2048), dim3(256), 0, stream, W, Wh);
  hipLaunchKernelGGL(k_splitz,  dim3(1024), dim3(256), 0, stream, z, Zh, Zl);
  hipLaunchKernelGGL(k_sz,      dim3(128),  dim3(256), 0, stream, z, S);
  hipLaunchKernelGGL(k_wsq,     dim3(32),   dim3(256), 0, stream, W, B, maxw);
  hipLaunchKernelGGL(k_main,    dim3(512),  dim3(512), 131072, stream,
                     Zh, Zl, Wh, S, B, maxw, idxb, cand, full, cnt);
  hipLaunchKernelGGL(k_cand,    dim3(128),  dim3(256), 0, stream, z, W, S, B, cand, cnt, idxb);
  hipLaunchKernelGGL(k_full,    dim3(2048), dim3(256), 74112, stream, z, W, S, B, full, cnt, fkey);
  hipLaunchKernelGGL(k_fullfin, dim3(128),  dim3(256), 0, stream, full, cnt, fkey, idxb);
  hipLaunchKernelGGL(k_zq,      dim3(512),  dim3(256), 0, stream, z, W, idxb, out, loss, hist);
  hipLaunchKernelGGL(k_final,   dim3(1),    dim3(256), 0, stream, hist, loss, out);
}